// Round 5
// baseline (195.905 us; speedup 1.0000x reference)
//
#include <hip/hip_runtime.h>
#include <hip/hip_cooperative_groups.h>
#include <math.h>

namespace cg = cooperative_groups;

#define EPSF 1e-6f

constexpr int B_  = 2;
constexpr int L_  = 1024;
constexpr int D_  = 512;
constexpr int H_  = 8;
constexpr int DH_ = 64;
constexpr int BL_ = B_ * L_;   // 2048
constexpr int BH_ = B_ * H_;   // 16
constexpr int CT_ = 64;        // chunk length
constexpr int NC_ = L_ / CT_;  // 16 chunks

typedef __attribute__((ext_vector_type(8))) short bf16x8;
typedef __attribute__((ext_vector_type(4))) float f32x4;

__device__ __forceinline__ unsigned short f2bf(float f) {
  union { float f; unsigned int u; } v; v.f = f;
  const unsigned int u = v.u;
  return (unsigned short)((u + 0x7FFFu + ((u >> 16) & 1u)) >> 16);  // RNE
}
__device__ __forceinline__ float bf2f(unsigned short u) {
  union { unsigned int u; float f; } v; v.u = ((unsigned int)u) << 16;
  return v.f;
}

// ---------------------------------------------------------------------------
// Fused projection GEMMs (z = 0:Q, 1:K, 2:V): out = sigmoid?(A @ W + b),
// permuted store to [B,H,L,Dh]; z<2 also writes per-(chunk,head) column sums.
// ---------------------------------------------------------------------------
__global__ __launch_bounds__(256) void proj3_k(const float* __restrict__ Qin,
                                               const float* __restrict__ Kin,
                                               const float* __restrict__ Vin,
                                               const float* __restrict__ Wq,
                                               const float* __restrict__ bq,
                                               const float* __restrict__ Wk,
                                               const float* __restrict__ bk,
                                               const float* __restrict__ Wv,
                                               const float* __restrict__ bv,
                                               float* __restrict__ Qb,
                                               float* __restrict__ Kb,
                                               float* __restrict__ Vb,
                                               float* __restrict__ sumQ,
                                               float* __restrict__ sumK) {
  const int z = blockIdx.z;
  const float* A    = (z == 0) ? Qin : (z == 1) ? Kin : Vin;
  const float* W    = (z == 0) ? Wq  : (z == 1) ? Wk  : Wv;
  const float* bias = (z == 0) ? bq  : (z == 1) ? bk  : bv;
  float* out        = (z == 0) ? Qb  : (z == 1) ? Kb  : Vb;
  float* csum       = (z == 0) ? sumQ : (z == 1) ? sumK : nullptr;
  const bool sig = (z < 2);

  __shared__ __align__(16) short Als[64 * 40];
  __shared__ __align__(16) short Bls[64 * 40];
  const int tid = threadIdx.x;
  const int m0 = blockIdx.x * 64, n0 = blockIdx.y * 64;
  const int arow = tid >> 2, akq = (tid & 3) << 3;
  const int bcol = tid & 63, bk0 = (tid >> 6) << 3;
  const int lane = tid & 63, wid = tid >> 6;
  const int wr = wid >> 1, wc = wid & 1;
  const int lrow = lane & 15, lk = (lane >> 4) << 3;

  f32x4 acc[2][2] = {{{0.f, 0.f, 0.f, 0.f}, {0.f, 0.f, 0.f, 0.f}},
                     {{0.f, 0.f, 0.f, 0.f}, {0.f, 0.f, 0.f, 0.f}}};
  float ra[8], rb[8];

  auto loadAB = [&](int kt) {
    const float4 f0 = *(const float4*)&A[(size_t)(m0 + arow) * D_ + kt + akq];
    const float4 f1 = *(const float4*)&A[(size_t)(m0 + arow) * D_ + kt + akq + 4];
    ra[0] = f0.x; ra[1] = f0.y; ra[2] = f0.z; ra[3] = f0.w;
    ra[4] = f1.x; ra[5] = f1.y; ra[6] = f1.z; ra[7] = f1.w;
    const float* gw = &W[(size_t)(kt + bk0) * D_ + n0 + bcol];
#pragma unroll
    for (int j = 0; j < 8; ++j) rb[j] = gw[(size_t)j * D_];
  };
  auto writeLDS = [&]() {
    bf16x8 pa, pb;
#pragma unroll
    for (int j = 0; j < 8; ++j) {
      pa[j] = (short)f2bf(ra[j]);
      pb[j] = (short)f2bf(rb[j]);
    }
    *(bf16x8*)&Als[arow * 40 + akq] = pa;
    *(bf16x8*)&Bls[bcol * 40 + bk0] = pb;
  };
  auto compute = [&]() {
    bf16x8 a0 = *(const bf16x8*)&Als[(wr * 32 + lrow) * 40 + lk];
    bf16x8 a1 = *(const bf16x8*)&Als[(wr * 32 + 16 + lrow) * 40 + lk];
    bf16x8 b0 = *(const bf16x8*)&Bls[(wc * 32 + lrow) * 40 + lk];
    bf16x8 b1 = *(const bf16x8*)&Bls[(wc * 32 + 16 + lrow) * 40 + lk];
    acc[0][0] = __builtin_amdgcn_mfma_f32_16x16x32_bf16(a0, b0, acc[0][0], 0, 0, 0);
    acc[0][1] = __builtin_amdgcn_mfma_f32_16x16x32_bf16(a0, b1, acc[0][1], 0, 0, 0);
    acc[1][0] = __builtin_amdgcn_mfma_f32_16x16x32_bf16(a1, b0, acc[1][0], 0, 0, 0);
    acc[1][1] = __builtin_amdgcn_mfma_f32_16x16x32_bf16(a1, b1, acc[1][1], 0, 0, 0);
  };

  loadAB(0);
  writeLDS();
  for (int kt = 32; kt < D_; kt += 32) {
    loadAB(kt);
    __syncthreads();
    compute();
    __syncthreads();
    writeLDS();
  }
  __syncthreads();
  compute();

  const int b = m0 >> 10, h = n0 >> 6;
  float psum[2] = {0.f, 0.f};
#pragma unroll
  for (int j = 0; j < 2; ++j) {
    const int col = n0 + wc * 32 + j * 16 + lrow;
    const float bv4 = bias[col];
    const int dh = col & 63;
#pragma unroll
    for (int i = 0; i < 2; ++i) {
#pragma unroll
      for (int r = 0; r < 4; ++r) {
        const int row = m0 + wr * 32 + i * 16 + (lane >> 4) * 4 + r;
        float x = acc[i][j][r] + bv4;
        if (sig) x = 1.0f / (1.0f + expf(-x));
        const int l = row & (L_ - 1);
        out[(((size_t)(b * H_ + h)) * L_ + l) * DH_ + dh] = x;
        psum[j] += x;
      }
    }
  }
  if (csum) {
    float* sumS = (float*)Als;
#pragma unroll
    for (int j = 0; j < 2; ++j) {
      psum[j] += __shfl_xor(psum[j], 16);
      psum[j] += __shfl_xor(psum[j], 32);
      if ((lane >> 4) == 0) sumS[wr * 64 + wc * 32 + j * 16 + lrow] = psum[j];
    }
    __syncthreads();
    if (tid < 64) {
      const int c = (m0 & (L_ - 1)) >> 6;
      const int bc = (b * H_ + h) * NC_ + c;
      csum[bc * DH_ + tid] = sumS[tid] + sumS[64 + tid];
    }
  }
}

// ---------------------------------------------------------------------------
// Cooperative mega-kernel: flow phase1 + phase2 + comp + chunk-KV + KV-prefix
// + attention, one block per (bh, chunk). grid 256 x 256 thr (4 waves).
// q,k staged in LDS once and reused by every phase; per-l scalars
// (qscale/si/so/salloc/e/comp) never leave LDS.
// ---------------------------------------------------------------------------
__global__ __launch_bounds__(256) void mega_k(const float* __restrict__ Qb,
                                              const float* __restrict__ Kb,
                                              const float* __restrict__ Vb,
                                              const float* __restrict__ sumQ,
                                              const float* __restrict__ sumK,
                                              float* __restrict__ sumQSI,
                                              float* __restrict__ sumKSO,
                                              float* __restrict__ sumE,
                                              float* __restrict__ KV,
                                              unsigned short* __restrict__ X) {
  cg::grid_group grid = cg::this_grid();
  const int bc = blockIdx.x, bh = bc >> 4, c = bc & (NC_ - 1);
  const int bb = bh >> 3, hh = bh & (H_ - 1);
  const int g = bc * CT_;
  const int tid = threadIdx.x, lane = tid & 63, w = tid >> 6;

  // LDS (static total 64512 B <= 64 KB limit)
  __shared__ __align__(16) float qS[64][68];       // raw q, later scaled to qp
  __shared__ __align__(16) float kS[64][68];       // raw k
  __shared__ __align__(16) float S[64][68];        // attn scores
  __shared__ unsigned short vbS[64][64];           // v * comp, bf16
  __shared__ float pqS[64], pkS[64];
  __shared__ float aS[4][64], bS[4][64];
  __shared__ float qscaleS[64], siS[64], soS[64];
  __shared__ float sallocS[64], eS[64], compS[64];

  // ---- stage q,k + phase-1 chunk-prefix ----
  for (int i = tid; i < CT_ * DH_; i += 256) {
    const int row = i >> 6, d = i & 63;
    qS[row][d] = Qb[(size_t)g * DH_ + i];
    kS[row][d] = Kb[(size_t)g * DH_ + i];
  }
  if (tid < 64) {
    float pq = 0.f, pk = 0.f;
    for (int cc = 0; cc < c; ++cc) {
      pq += sumQ[(bh * NC_ + cc) * DH_ + tid];
      pk += sumK[(bh * NC_ + cc) * DH_ + tid];
    }
    pqS[tid] = pq; pkS[tid] = pk;
  }
  __syncthreads();

  // ---- phase 1: a,b via 4-wave d-split scans (wave w: d in [16w,16w+16)) ----
  {
    float ap = 0.f, bp = 0.f;
    for (int dd = 0; dd < 16; ++dd) {
      const int d = w * 16 + dd;
      const float qv = qS[lane][d];
      const float kv = kS[lane][d];
      float ck = kv, cq = qv;
#pragma unroll
      for (int off = 1; off < 64; off <<= 1) {
        const float t1 = __shfl_up(ck, off);
        const float t2 = __shfl_up(cq, off);
        ck += (lane >= off) ? t1 : 0.f;
        cq += (lane >= off) ? t2 : 0.f;
      }
      ck += pkS[d];
      cq += pqS[d];
      ap += (qv + EPSF) * (ck + EPSF);
      bp += (kv + EPSF) * (cq + EPSF);
    }
    aS[w][lane] = ap; bS[w][lane] = bp;
  }
  __syncthreads();
  const float normal = (float)(c * CT_ + lane + 1);
  float si, so;
  {
    const float a = aS[0][lane] + aS[1][lane] + aS[2][lane] + aS[3][lane];
    const float b = bS[0][lane] + bS[1][lane] + bS[2][lane] + bS[3][lane];
    si = normal / a; so = normal / b;
    if (w == 0) { qscaleS[lane] = 1.0f / a; siS[lane] = si; soS[lane] = so; }
  }
  __syncthreads();
  // chunk sums of q*si, k*so (thread (w, d=lane): l-range per wave)
  {
    float sq = 0.f, sk = 0.f;
#pragma unroll
    for (int li = 0; li < 16; ++li) {
      const int l = w * 16 + li;
      sq += qS[l][lane] * siS[l];
      sk += kS[l][lane] * soS[l];
    }
    aS[w][lane] = sq; bS[w][lane] = sk;
  }
  __syncthreads();
  if (tid < 64) {
    sumQSI[bc * DH_ + tid] = aS[0][tid] + aS[1][tid] + aS[2][tid] + aS[3][tid];
    sumKSO[bc * DH_ + tid] = bS[0][tid] + bS[1][tid] + bS[2][tid] + bS[3][tid];
  }
  grid.sync();

  // ---- phase 2: conserved sink/source ----
  if (tid < 64) {
    float pq = 0.f, pk = 0.f;
    for (int cc = 0; cc < c; ++cc) {
      pq += sumQSI[(bh * NC_ + cc) * DH_ + tid];
      pk += sumKSO[(bh * NC_ + cc) * DH_ + tid];
    }
    pqS[tid] = pq; pkS[tid] = pk;
  }
  __syncthreads();
  {
    float c1p = 0.f, c2p = 0.f;
    for (int dd = 0; dd < 16; ++dd) {
      const int d = w * 16 + dd;
      const float qv = qS[lane][d];
      const float kv = kS[lane][d];
      float ckso = kv * so, cqsi = qv * si;
#pragma unroll
      for (int off = 1; off < 64; off <<= 1) {
        const float t1 = __shfl_up(ckso, off);
        const float t2 = __shfl_up(cqsi, off);
        ckso += (lane >= off) ? t1 : 0.f;
        cqsi += (lane >= off) ? t2 : 0.f;
      }
      ckso += pkS[d];
      cqsi += pqS[d];
      c1p += (qv + EPSF) * (ckso + EPSF);
      c2p += (kv + EPSF) * (cqsi + EPSF);
    }
    aS[w][lane] = c1p; bS[w][lane] = c2p;
  }
  __syncthreads();
  {
    const float c1 = aS[0][lane] + aS[1][lane] + aS[2][lane] + aS[3][lane];
    const float c2 = bS[0][lane] + bS[1][lane] + bS[2][lane] + bS[3][lane];
    const float cs_sink = c1 / normal;
    float cs_src = c2 / normal;
    cs_src = fminf(1.0f, fmaxf(-1.0f, cs_src));
    const float e = expf(cs_src);
    if (w == 0) {
      sallocS[lane] = 1.0f / (1.0f + expf(-cs_sink));
      eS[lane] = e;
      float tot = e;
#pragma unroll
      for (int off = 32; off; off >>= 1) tot += __shfl_xor(tot, off);
      if (lane == 0) sumE[bc] = tot;
    }
  }
  grid.sync();

  // ---- competition + staging for KV/attention ----
  if (w == 0) {
    float se = (lane < c) ? sumE[bh * NC_ + lane] : 0.f;
#pragma unroll
    for (int off = 32; off; off >>= 1) se += __shfl_xor(se, off);
    float s = eS[lane];
#pragma unroll
    for (int off = 1; off < 64; off <<= 1) {
      const float t = __shfl_up(s, off);
      s += (lane >= off) ? t : 0.f;
    }
    compS[lane] = eS[lane] / (se + s) * normal;
  }
  __syncthreads();
  for (int i = tid; i < CT_ * DH_; i += 256) {
    const int row = i >> 6, d = i & 63;
    qS[row][d] *= qscaleS[row];                              // qS -> qp in place
    vbS[row][d] = f2bf(Vb[(size_t)g * DH_ + i] * compS[row]);
  }
  __syncthreads();

  // ---- chunk-local KV: KV[bc][d][m] = sum_l k[l,d] * v'[l,m] ----
  {
    const int m = lane, dg = w;
    float acck[16] = {};
    for (int l = 0; l < CT_; ++l) {
      const float vm = bf2f(vbS[l][m]);
#pragma unroll
      for (int i = 0; i < 16; ++i) acck[i] += kS[l][dg * 16 + i] * vm;
    }
    float* outp = KV + ((size_t)bc * DH_ + dg * 16) * DH_ + m;
#pragma unroll
    for (int i = 0; i < 16; ++i) outp[i * DH_] = acck[i];
  }
  grid.sync();

  // ---- distributed exclusive KV prefix (1 element/thread, 16-step) ----
  {
    const int p = (bc & 15) * 256 + tid;
    const size_t base = (size_t)(bc >> 4) * NC_ * DH_ * DH_ + p;
    float run = 0.f;
#pragma unroll
    for (int cc = 0; cc < NC_; ++cc) {
      const float t = KV[base + (size_t)cc * DH_ * DH_];
      KV[base + (size_t)cc * DH_ * DH_] = run;
      run += t;
    }
  }
  grid.sync();

  // ---- attention ----
  {
    const int m = lane;
    float acc[16] = {};
    // inter-chunk: qp @ KVprefix
    const float* kvp = KV + (size_t)bc * DH_ * DH_;
    for (int d4 = 0; d4 < 16; ++d4) {
      float kvv[4];
#pragma unroll
      for (int e = 0; e < 4; ++e) kvv[e] = kvp[(d4 * 4 + e) * DH_ + m];
#pragma unroll
      for (int i = 0; i < 16; ++i) {
        const float4 q4 = *(const float4*)&qS[w * 16 + i][d4 * 4];
        acc[i] += q4.x * kvv[0] + q4.y * kvv[1] + q4.z * kvv[2] + q4.w * kvv[3];
      }
    }
    // scores
    {
      float sc[16] = {};
      for (int d4 = 0; d4 < 16; ++d4) {
        const float4 q4 = *(const float4*)&qS[m][d4 * 4];
#pragma unroll
        for (int i = 0; i < 16; ++i) {
          const float4 k4 = *(const float4*)&kS[w * 16 + i][d4 * 4];
          sc[i] += q4.x * k4.x + q4.y * k4.y + q4.z * k4.z + q4.w * k4.w;
        }
      }
#pragma unroll
      for (int i = 0; i < 16; ++i) {
        const int j = w * 16 + i;
        S[m][j] = (j <= m) ? sc[i] : 0.0f;
      }
    }
    __syncthreads();
    // intra-chunk: S @ v'
    for (int j4 = 0; j4 < 16; ++j4) {
      float vv[4];
#pragma unroll
      for (int e = 0; e < 4; ++e) vv[e] = bf2f(vbS[j4 * 4 + e][m]);
#pragma unroll
      for (int i = 0; i < 16; ++i) {
        const float4 s4 = *(const float4*)&S[w * 16 + i][j4 * 4];
        acc[i] += s4.x * vv[0] + s4.y * vv[1] + s4.z * vv[2] + s4.w * vv[3];
      }
    }
    // epilogue: * sink_allocation, bf16 store to X [B, L, H*Dh]
#pragma unroll
    for (int i = 0; i < 16; ++i) {
      const int l = w * 16 + i;
      const float x = acc[i] * sallocS[l];
      X[((size_t)(bb * L_ + c * CT_ + l)) * D_ + hh * DH_ + m] = f2bf(x);
    }
  }
}

// ---------------------------------------------------------------------------
// Output GEMM: d_out = X(bf16) @ Wo + bo.
// ---------------------------------------------------------------------------
__global__ __launch_bounds__(256) void gemm_out_k(const unsigned short* __restrict__ A,
                                                  const float* __restrict__ W,
                                                  const float* __restrict__ bias,
                                                  float* __restrict__ out) {
  __shared__ __align__(16) short Als[64 * 40];
  __shared__ __align__(16) short Bls[64 * 40];
  const int tid = threadIdx.x;
  const int m0 = blockIdx.x * 64, n0 = blockIdx.y * 64;
  const int arow = tid >> 2, akq = (tid & 3) << 3;
  const int bcol = tid & 63, bk0 = (tid >> 6) << 3;
  const int lane = tid & 63, wid = tid >> 6;
  const int wr = wid >> 1, wc = wid & 1;
  const int lrow = lane & 15, lk = (lane >> 4) << 3;

  f32x4 acc[2][2] = {{{0.f, 0.f, 0.f, 0.f}, {0.f, 0.f, 0.f, 0.f}},
                     {{0.f, 0.f, 0.f, 0.f}, {0.f, 0.f, 0.f, 0.f}}};
  bf16x8 pa;
  float rb[8];
  auto loadAB = [&](int kt) {
    pa = *(const bf16x8*)&A[(size_t)(m0 + arow) * D_ + kt + akq];  // bf16 direct
    const float* gw = &W[(size_t)(kt + bk0) * D_ + n0 + bcol];
#pragma unroll
    for (int j = 0; j < 8; ++j) rb[j] = gw[(size_t)j * D_];
  };
  auto writeLDS = [&]() {
    bf16x8 pb;
#pragma unroll
    for (int j = 0; j < 8; ++j) pb[j] = (short)f2bf(rb[j]);
    *(bf16x8*)&Als[arow * 40 + akq] = pa;
    *(bf16x8*)&Bls[bcol * 40 + bk0] = pb;
  };
  auto compute = [&]() {
    bf16x8 a0 = *(const bf16x8*)&Als[(wr * 32 + lrow) * 40 + lk];
    bf16x8 a1 = *(const bf16x8*)&Als[(wr * 32 + 16 + lrow) * 40 + lk];
    bf16x8 b0 = *(const bf16x8*)&Bls[(wc * 32 + lrow) * 40 + lk];
    bf16x8 b1 = *(const bf16x8*)&Bls[(wc * 32 + 16 + lrow) * 40 + lk];
    acc[0][0] = __builtin_amdgcn_mfma_f32_16x16x32_bf16(a0, b0, acc[0][0], 0, 0, 0);
    acc[0][1] = __builtin_amdgcn_mfma_f32_16x16x32_bf16(a0, b1, acc[0][1], 0, 0, 0);
    acc[1][0] = __builtin_amdgcn_mfma_f32_16x16x32_bf16(a1, b0, acc[1][0], 0, 0, 0);
    acc[1][1] = __builtin_amdgcn_mfma_f32_16x16x32_bf16(a1, b1, acc[1][1], 0, 0, 0);
  };

  loadAB(0);
  writeLDS();
  for (int kt = 32; kt < D_; kt += 32) {
    loadAB(kt);
    __syncthreads();
    compute();
    __syncthreads();
    writeLDS();
  }
  __syncthreads();
  compute();

#pragma unroll
  for (int j = 0; j < 2; ++j) {
    const int col = n0 + wc * 32 + j * 16 + lrow;
    const float bv4 = bias[col];
#pragma unroll
    for (int i = 0; i < 2; ++i) {
#pragma unroll
      for (int r = 0; r < 4; ++r) {
        const int row = m0 + wr * 32 + i * 16 + (lane >> 4) * 4 + r;
        out[(size_t)row * D_ + col] = acc[i][j][r] + bv4;
      }
    }
  }
}

// ---------------------------------------------------------------------------
extern "C" void kernel_launch(void* const* d_in, const int* in_sizes, int n_in,
                              void* d_out, int out_size, void* d_ws, size_t ws_size,
                              hipStream_t stream) {
  (void)in_sizes; (void)n_in; (void)out_size; (void)ws_size;
  const float* queries = (const float*)d_in[0];
  const float* keys    = (const float*)d_in[1];
  const float* values  = (const float*)d_in[2];
  const float* Wq = (const float*)d_in[3];
  const float* bq = (const float*)d_in[4];
  const float* Wk = (const float*)d_in[5];
  const float* bk = (const float*)d_in[6];
  const float* Wv = (const float*)d_in[7];
  const float* bv = (const float*)d_in[8];
  const float* Wo = (const float*)d_in[9];
  const float* bo = (const float*)d_in[10];

  float* ws = (float*)d_ws;
  const size_t seg = (size_t)BH_ * L_ * DH_;  // 1,048,576 floats
  float* Qb  = ws;
  float* Kb  = Qb + seg;
  float* Vb  = Kb + seg;
  float* KVb = Vb + seg;                        // [BH, NC, DH, DH]
  float* p   = KVb + (size_t)BH_ * NC_ * DH_ * DH_;
  float* sumQ   = p; p += BH_ * NC_ * DH_;
  float* sumK   = p; p += BH_ * NC_ * DH_;
  float* sumQSI = p; p += BH_ * NC_ * DH_;
  float* sumKSO = p; p += BH_ * NC_ * DH_;
  float* sumE   = p; p += BH_ * NC_;
  unsigned short* Xb16 = (unsigned short*)p;    // [BL, D] bf16

  proj3_k<<<dim3(BL_ / 64, D_ / 64, 3), 256, 0, stream>>>(
      queries, keys, values, Wq, bq, Wk, bk, Wv, bv, Qb, Kb, Vb, sumQ, sumK);

  void* margs[] = {(void*)&Qb, (void*)&Kb, (void*)&Vb, (void*)&sumQ, (void*)&sumK,
                   (void*)&sumQSI, (void*)&sumKSO, (void*)&sumE, (void*)&KVb,
                   (void*)&Xb16};
  hipLaunchCooperativeKernel((const void*)mega_k, dim3(BH_ * NC_), dim3(256),
                             margs, 0, stream);

  gemm_out_k<<<dim3(BL_ / 64, D_ / 64), 256, 0, stream>>>(Xb16, Wo, bo, (float*)d_out);
}

// Round 6
// 125.199 us; speedup vs baseline: 1.5648x; 1.5648x over previous
//
#include <hip/hip_runtime.h>
#include <math.h>

#define EPSF 1e-6f

constexpr int B_  = 2;
constexpr int L_  = 1024;
constexpr int D_  = 512;
constexpr int H_  = 8;
constexpr int DH_ = 64;
constexpr int BL_ = B_ * L_;   // 2048
constexpr int BH_ = B_ * H_;   // 16
constexpr int CT_ = 64;        // chunk length
constexpr int NC_ = L_ / CT_;  // 16 chunks

typedef __attribute__((ext_vector_type(8))) short bf16x8;
typedef __attribute__((ext_vector_type(4))) float f32x4;

__device__ __forceinline__ unsigned short f2bf(float f) {
  union { float f; unsigned int u; } v; v.f = f;
  const unsigned int u = v.u;
  return (unsigned short)((u + 0x7FFFu + ((u >> 16) & 1u)) >> 16);  // RNE
}
__device__ __forceinline__ float bf2f(unsigned short u) {
  union { unsigned int u; float f; } v; v.u = ((unsigned int)u) << 16;
  return v.f;
}

// ---------------------------------------------------------------------------
// Fused projection GEMMs (z = 0:Q, 1:K, 2:V): out = sigmoid?(A @ W + b),
// permuted store to [B,H,L,Dh]; z<2 also writes per-(chunk,head) column sums.
// ---------------------------------------------------------------------------
__global__ __launch_bounds__(256) void proj3_k(const float* __restrict__ Qin,
                                               const float* __restrict__ Kin,
                                               const float* __restrict__ Vin,
                                               const float* __restrict__ Wq,
                                               const float* __restrict__ bq,
                                               const float* __restrict__ Wk,
                                               const float* __restrict__ bk,
                                               const float* __restrict__ Wv,
                                               const float* __restrict__ bv,
                                               float* __restrict__ Qb,
                                               float* __restrict__ Kb,
                                               float* __restrict__ Vb,
                                               float* __restrict__ sumQ,
                                               float* __restrict__ sumK) {
  const int z = blockIdx.z;
  const float* A    = (z == 0) ? Qin : (z == 1) ? Kin : Vin;
  const float* W    = (z == 0) ? Wq  : (z == 1) ? Wk  : Wv;
  const float* bias = (z == 0) ? bq  : (z == 1) ? bk  : bv;
  float* out        = (z == 0) ? Qb  : (z == 1) ? Kb  : Vb;
  float* csum       = (z == 0) ? sumQ : (z == 1) ? sumK : nullptr;
  const bool sig = (z < 2);

  __shared__ __align__(16) short Als[64 * 40];
  __shared__ __align__(16) short Bls[64 * 40];
  const int tid = threadIdx.x;
  const int m0 = blockIdx.x * 64, n0 = blockIdx.y * 64;
  const int arow = tid >> 2, akq = (tid & 3) << 3;
  const int bcol = tid & 63, bk0 = (tid >> 6) << 3;
  const int lane = tid & 63, wid = tid >> 6;
  const int wr = wid >> 1, wc = wid & 1;
  const int lrow = lane & 15, lk = (lane >> 4) << 3;

  f32x4 acc[2][2] = {{{0.f, 0.f, 0.f, 0.f}, {0.f, 0.f, 0.f, 0.f}},
                     {{0.f, 0.f, 0.f, 0.f}, {0.f, 0.f, 0.f, 0.f}}};
  float ra[8], rb[8];

  auto loadAB = [&](int kt) {
    const float4 f0 = *(const float4*)&A[(size_t)(m0 + arow) * D_ + kt + akq];
    const float4 f1 = *(const float4*)&A[(size_t)(m0 + arow) * D_ + kt + akq + 4];
    ra[0] = f0.x; ra[1] = f0.y; ra[2] = f0.z; ra[3] = f0.w;
    ra[4] = f1.x; ra[5] = f1.y; ra[6] = f1.z; ra[7] = f1.w;
    const float* gw = &W[(size_t)(kt + bk0) * D_ + n0 + bcol];
#pragma unroll
    for (int j = 0; j < 8; ++j) rb[j] = gw[(size_t)j * D_];
  };
  auto writeLDS = [&]() {
    bf16x8 pa, pb;
#pragma unroll
    for (int j = 0; j < 8; ++j) {
      pa[j] = (short)f2bf(ra[j]);
      pb[j] = (short)f2bf(rb[j]);
    }
    *(bf16x8*)&Als[arow * 40 + akq] = pa;
    *(bf16x8*)&Bls[bcol * 40 + bk0] = pb;
  };
  auto compute = [&]() {
    bf16x8 a0 = *(const bf16x8*)&Als[(wr * 32 + lrow) * 40 + lk];
    bf16x8 a1 = *(const bf16x8*)&Als[(wr * 32 + 16 + lrow) * 40 + lk];
    bf16x8 b0 = *(const bf16x8*)&Bls[(wc * 32 + lrow) * 40 + lk];
    bf16x8 b1 = *(const bf16x8*)&Bls[(wc * 32 + 16 + lrow) * 40 + lk];
    acc[0][0] = __builtin_amdgcn_mfma_f32_16x16x32_bf16(a0, b0, acc[0][0], 0, 0, 0);
    acc[0][1] = __builtin_amdgcn_mfma_f32_16x16x32_bf16(a0, b1, acc[0][1], 0, 0, 0);
    acc[1][0] = __builtin_amdgcn_mfma_f32_16x16x32_bf16(a1, b0, acc[1][0], 0, 0, 0);
    acc[1][1] = __builtin_amdgcn_mfma_f32_16x16x32_bf16(a1, b1, acc[1][1], 0, 0, 0);
  };

  loadAB(0);
  writeLDS();
  for (int kt = 32; kt < D_; kt += 32) {
    loadAB(kt);
    __syncthreads();
    compute();
    __syncthreads();
    writeLDS();
  }
  __syncthreads();
  compute();

  const int b = m0 >> 10, h = n0 >> 6;
  float psum[2] = {0.f, 0.f};
#pragma unroll
  for (int j = 0; j < 2; ++j) {
    const int col = n0 + wc * 32 + j * 16 + lrow;
    const float bv4 = bias[col];
    const int dh = col & 63;
#pragma unroll
    for (int i = 0; i < 2; ++i) {
#pragma unroll
      for (int r = 0; r < 4; ++r) {
        const int row = m0 + wr * 32 + i * 16 + (lane >> 4) * 4 + r;
        float x = acc[i][j][r] + bv4;
        if (sig) x = 1.0f / (1.0f + expf(-x));
        const int l = row & (L_ - 1);
        out[(((size_t)(b * H_ + h)) * L_ + l) * DH_ + dh] = x;
        psum[j] += x;
      }
    }
  }
  if (csum) {
    float* sumS = (float*)Als;
#pragma unroll
    for (int j = 0; j < 2; ++j) {
      psum[j] += __shfl_xor(psum[j], 16);
      psum[j] += __shfl_xor(psum[j], 32);
      if ((lane >> 4) == 0) sumS[wr * 64 + wc * 32 + j * 16 + lrow] = psum[j];
    }
    __syncthreads();
    if (tid < 64) {
      const int c = (m0 & (L_ - 1)) >> 6;
      const int bc = (b * H_ + h) * NC_ + c;
      csum[bc * DH_ + tid] = sumS[tid] + sumS[64 + tid];
    }
  }
}

// ---------------------------------------------------------------------------
// Flow phase 1: 256 thr, 4-wave d-split scans. LDS pad 65 -> conflict-free.
// ---------------------------------------------------------------------------
__global__ __launch_bounds__(256) void flow_phase1_k(const float* __restrict__ Qb,
                                                     const float* __restrict__ Kb,
                                                     const float* __restrict__ sumQ,
                                                     const float* __restrict__ sumK,
                                                     float* __restrict__ qscale,
                                                     float* __restrict__ si_a,
                                                     float* __restrict__ so_a,
                                                     float* __restrict__ sumQSI,
                                                     float* __restrict__ sumKSO) {
  const int bc = blockIdx.x, bh = bc >> 4, c = bc & (NC_ - 1);
  const int g = bc * CT_;
  const int tid = threadIdx.x, lane = tid & 63, w = tid >> 6;
  __shared__ float qS[64][65], kS[64][65];
  __shared__ float pqS[64], pkS[64];
  __shared__ float aS[4][64], bS[4][64];
  __shared__ float siS[64], soS[64];
  for (int i = tid; i < CT_ * DH_; i += 256) {
    const int row = i >> 6, d = i & 63;
    qS[row][d] = Qb[(size_t)g * DH_ + i];
    kS[row][d] = Kb[(size_t)g * DH_ + i];
  }
  if (tid < 64) {
    float pq = 0.f, pk = 0.f;
    for (int cc = 0; cc < c; ++cc) {
      pq += sumQ[(bh * NC_ + cc) * DH_ + tid];
      pk += sumK[(bh * NC_ + cc) * DH_ + tid];
    }
    pqS[tid] = pq; pkS[tid] = pk;
  }
  __syncthreads();
  float ap = 0.f, bp = 0.f;
  for (int dd = 0; dd < 16; ++dd) {
    const int d = w * 16 + dd;
    const float qv = qS[lane][d];
    const float kv = kS[lane][d];
    float ck = kv, cq = qv;
#pragma unroll
    for (int off = 1; off < 64; off <<= 1) {
      const float t1 = __shfl_up(ck, off);
      const float t2 = __shfl_up(cq, off);
      ck += (lane >= off) ? t1 : 0.f;
      cq += (lane >= off) ? t2 : 0.f;
    }
    ck += pkS[d];
    cq += pqS[d];
    ap += (qv + EPSF) * (ck + EPSF);
    bp += (kv + EPSF) * (cq + EPSF);
  }
  aS[w][lane] = ap; bS[w][lane] = bp;
  __syncthreads();
  const float normal = (float)(c * CT_ + lane + 1);
  if (w == 0) {
    const float a = aS[0][lane] + aS[1][lane] + aS[2][lane] + aS[3][lane];
    const float b = bS[0][lane] + bS[1][lane] + bS[2][lane] + bS[3][lane];
    const float si = normal / a, so = normal / b;
    qscale[g + lane] = 1.0f / a;
    si_a[g + lane] = si;
    so_a[g + lane] = so;
    siS[lane] = si; soS[lane] = so;
  }
  __syncthreads();
  float sq = 0.f, sk = 0.f;
#pragma unroll
  for (int li = 0; li < 16; ++li) {
    const int l = w * 16 + li;
    sq += qS[l][lane] * siS[l];
    sk += kS[l][lane] * soS[l];
  }
  aS[w][lane] = sq; bS[w][lane] = sk;
  __syncthreads();
  if (tid < 64) {
    sumQSI[bc * DH_ + tid] = aS[0][tid] + aS[1][tid] + aS[2][tid] + aS[3][tid];
    sumKSO[bc * DH_ + tid] = bS[0][tid] + bS[1][tid] + bS[2][tid] + bS[3][tid];
  }
}

// ---------------------------------------------------------------------------
// Flow phase 2: 256 thr, 4-wave d-split. Outputs salloc, e, chunk sumE.
// ---------------------------------------------------------------------------
__global__ __launch_bounds__(256) void flow_phase2_k(const float* __restrict__ Qb,
                                                     const float* __restrict__ Kb,
                                                     const float* __restrict__ sumQSI,
                                                     const float* __restrict__ sumKSO,
                                                     const float* __restrict__ si_a,
                                                     const float* __restrict__ so_a,
                                                     float* __restrict__ salloc,
                                                     float* __restrict__ e_a,
                                                     float* __restrict__ sumE) {
  const int bc = blockIdx.x, bh = bc >> 4, c = bc & (NC_ - 1);
  const int g = bc * CT_;
  const int tid = threadIdx.x, lane = tid & 63, w = tid >> 6;
  __shared__ float qS[64][65], kS[64][65];
  __shared__ float pqS[64], pkS[64];
  __shared__ float aS[4][64], bS[4][64];
  for (int i = tid; i < CT_ * DH_; i += 256) {
    const int row = i >> 6, d = i & 63;
    qS[row][d] = Qb[(size_t)g * DH_ + i];
    kS[row][d] = Kb[(size_t)g * DH_ + i];
  }
  if (tid < 64) {
    float pq = 0.f, pk = 0.f;
    for (int cc = 0; cc < c; ++cc) {
      pq += sumQSI[(bh * NC_ + cc) * DH_ + tid];
      pk += sumKSO[(bh * NC_ + cc) * DH_ + tid];
    }
    pqS[tid] = pq; pkS[tid] = pk;
  }
  __syncthreads();
  const float si = si_a[g + lane];
  const float so = so_a[g + lane];
  float c1p = 0.f, c2p = 0.f;
  for (int dd = 0; dd < 16; ++dd) {
    const int d = w * 16 + dd;
    const float qv = qS[lane][d];
    const float kv = kS[lane][d];
    float ckso = kv * so, cqsi = qv * si;
#pragma unroll
    for (int off = 1; off < 64; off <<= 1) {
      const float t1 = __shfl_up(ckso, off);
      const float t2 = __shfl_up(cqsi, off);
      ckso += (lane >= off) ? t1 : 0.f;
      cqsi += (lane >= off) ? t2 : 0.f;
    }
    ckso += pkS[d];
    cqsi += pqS[d];
    c1p += (qv + EPSF) * (ckso + EPSF);
    c2p += (kv + EPSF) * (cqsi + EPSF);
  }
  aS[w][lane] = c1p; bS[w][lane] = c2p;
  __syncthreads();
  if (w == 0) {
    const float c1 = aS[0][lane] + aS[1][lane] + aS[2][lane] + aS[3][lane];
    const float c2 = bS[0][lane] + bS[1][lane] + bS[2][lane] + bS[3][lane];
    const float normal = (float)(c * CT_ + lane + 1);
    const float cs_sink = c1 / normal;
    salloc[g + lane] = 1.0f / (1.0f + expf(-cs_sink));
    float cs_src = c2 / normal;
    cs_src = fminf(1.0f, fmaxf(-1.0f, cs_src));
    const float e = expf(cs_src);
    e_a[g + lane] = e;
    float tot = e;
#pragma unroll
    for (int off = 32; off; off >>= 1) tot += __shfl_xor(tot, off);
    if (lane == 0) sumE[bc] = tot;
  }
}

// ---------------------------------------------------------------------------
// Fused: source_competition (inline prefix of sumE) + chunk-local KV sums.
// ---------------------------------------------------------------------------
__global__ __launch_bounds__(256) void flow_ckv_k(const float* __restrict__ K,
                                                  const float* __restrict__ V,
                                                  const float* __restrict__ e_a,
                                                  const float* __restrict__ sumE,
                                                  float* __restrict__ comp,
                                                  float* __restrict__ KV) {
  const int bc = blockIdx.x, bh = bc >> 4, c = bc & (NC_ - 1);
  const int g = bc * CT_;
  const int tid = threadIdx.x;
  __shared__ float compS[CT_];
  __shared__ float kb[CT_][DH_];
  __shared__ float vb[CT_][DH_];
  if (tid < 64) {
    const int lane = tid;
    const float e = e_a[g + lane];
    float se = (lane < c) ? sumE[bh * NC_ + lane] : 0.f;
#pragma unroll
    for (int off = 32; off; off >>= 1) se += __shfl_xor(se, off);
    float s = e;
#pragma unroll
    for (int off = 1; off < 64; off <<= 1) {
      const float t = __shfl_up(s, off);
      s += (lane >= off) ? t : 0.f;
    }
    const float cf = e / (se + s) * (float)(c * CT_ + lane + 1);
    compS[lane] = cf;
    comp[g + lane] = cf;
  }
  __syncthreads();
  const float* k = K + (size_t)g * DH_;
  const float* v = V + (size_t)g * DH_;
  for (int i = tid; i < CT_ * DH_; i += 256) {
    const int l = i >> 6;
    kb[l][i & 63] = k[i];
    vb[l][i & 63] = v[i] * compS[l];
  }
  __syncthreads();
  const int m = tid & 63, dg = tid >> 6;
  float acc[16] = {};
  for (int l = 0; l < CT_; ++l) {
    const float vm = vb[l][m];
#pragma unroll
    for (int i = 0; i < 16; ++i) acc[i] += kb[l][dg * 16 + i] * vm;
  }
  float* out = KV + ((size_t)bc * DH_ + dg * 16) * DH_ + m;
#pragma unroll
  for (int i = 0; i < 16; ++i) out[i * DH_] = acc[i];
}

// ---------------------------------------------------------------------------
// Per-chunk attention with inline KV-prefix accumulation (raw chunk KV in,
// prefix built in LDS; S reuses the same LDS after a barrier).
// out = (qp @ KVprefix + tril(qp k^T) v') * salloc, bf16 store to X.
// ---------------------------------------------------------------------------
__global__ __launch_bounds__(256) void attn_k(const float* __restrict__ Q,
                                              const float* __restrict__ K,
                                              const float* __restrict__ V,
                                              const float* __restrict__ KV,
                                              const float* __restrict__ qscale,
                                              const float* __restrict__ salloc,
                                              const float* __restrict__ comp,
                                              unsigned short* __restrict__ X) {
  const int bc = blockIdx.x;
  const int bh = bc >> 4, c = bc & (NC_ - 1);
  const int bb = bh >> 3, hh = bh & (H_ - 1);
  const int g = bc * CT_;
  __shared__ float qp[CT_][DH_ + 4];   // padded for float4 (16B-aligned rows)
  __shared__ float kb[CT_][DH_];       // broadcast reads only
  __shared__ float buf[CT_ * (DH_ + 4)];  // union: KVp [64][68], then S [64][68]
  const int tid = threadIdx.x;
  for (int i = tid; i < CT_ * DH_; i += 256) {
    const int l = i >> 6, d = i & 63;
    qp[l][d] = Q[(size_t)g * DH_ + i] * qscale[g + l];
    kb[l][d] = K[(size_t)g * DH_ + i];
  }
  // KV prefix for this (bh, c): sum of raw chunk KVs of chunks < c
  {
    const float* kvbh = KV + (size_t)bh * NC_ * DH_ * DH_;
    for (int idx = tid; idx < DH_ * DH_; idx += 256) {
      float s = 0.f;
      for (int cc = 0; cc < c; ++cc) s += kvbh[(size_t)cc * DH_ * DH_ + idx];
      buf[(idx >> 6) * (DH_ + 4) + (idx & 63)] = s;
    }
  }
  __syncthreads();
  const int m = tid & 63, w = tid >> 6;
  float acc[16] = {};
  // inter-chunk: qp @ KVprefix (from LDS)
  for (int d4 = 0; d4 < 16; ++d4) {
    float kvv[4];
#pragma unroll
    for (int e = 0; e < 4; ++e) kvv[e] = buf[(d4 * 4 + e) * (DH_ + 4) + m];
#pragma unroll
    for (int i = 0; i < 16; ++i) {
      const float4 q4 = *(const float4*)&qp[w * 16 + i][d4 * 4];
      acc[i] += q4.x * kvv[0] + q4.y * kvv[1] + q4.z * kvv[2] + q4.w * kvv[3];
    }
  }
  // scores into registers
  float sc[16] = {};
  for (int d4 = 0; d4 < 16; ++d4) {
    const float4 q4 = *(const float4*)&qp[m][d4 * 4];
#pragma unroll
    for (int i = 0; i < 16; ++i) {
      const float4 k4 = *(const float4*)&kb[w * 16 + i][d4 * 4];
      sc[i] += q4.x * k4.x + q4.y * k4.y + q4.z * k4.z + q4.w * k4.w;
    }
  }
  __syncthreads();  // all KVp reads done; safe to overwrite buf with S
#pragma unroll
  for (int i = 0; i < 16; ++i) {
    const int j = w * 16 + i;
    buf[m * (DH_ + 4) + j] = (j <= m) ? sc[i] : 0.0f;
  }
  __syncthreads();
  // intra-chunk: S @ v'
  for (int j4 = 0; j4 < 16; ++j4) {
    float vv[4];
#pragma unroll
    for (int e = 0; e < 4; ++e) {
      const int j = j4 * 4 + e;
      vv[e] = V[(size_t)(g + j) * DH_ + m] * comp[g + j];
    }
#pragma unroll
    for (int i = 0; i < 16; ++i) {
      const float4 s4 = *(const float4*)&buf[(w * 16 + i) * (DH_ + 4) + j4 * 4];
      acc[i] += s4.x * vv[0] + s4.y * vv[1] + s4.z * vv[2] + s4.w * vv[3];
    }
  }
#pragma unroll
  for (int i = 0; i < 16; ++i) {
    const int l = w * 16 + i;
    const float x = acc[i] * salloc[g + l];
    X[((size_t)(bb * L_ + c * CT_ + l)) * D_ + hh * DH_ + m] = f2bf(x);
  }
}

// ---------------------------------------------------------------------------
// Output GEMM: d_out = X(bf16) @ Wo + bo.
// ---------------------------------------------------------------------------
__global__ __launch_bounds__(256) void gemm_out_k(const unsigned short* __restrict__ A,
                                                  const float* __restrict__ W,
                                                  const float* __restrict__ bias,
                                                  float* __restrict__ out) {
  __shared__ __align__(16) short Als[64 * 40];
  __shared__ __align__(16) short Bls[64 * 40];
  const int tid = threadIdx.x;
  const int m0 = blockIdx.x * 64, n0 = blockIdx.y * 64;
  const int arow = tid >> 2, akq = (tid & 3) << 3;
  const int bcol = tid & 63, bk0 = (tid >> 6) << 3;
  const int lane = tid & 63, wid = tid >> 6;
  const int wr = wid >> 1, wc = wid & 1;
  const int lrow = lane & 15, lk = (lane >> 4) << 3;

  f32x4 acc[2][2] = {{{0.f, 0.f, 0.f, 0.f}, {0.f, 0.f, 0.f, 0.f}},
                     {{0.f, 0.f, 0.f, 0.f}, {0.f, 0.f, 0.f, 0.f}}};
  bf16x8 pa;
  float rb[8];
  auto loadAB = [&](int kt) {
    pa = *(const bf16x8*)&A[(size_t)(m0 + arow) * D_ + kt + akq];
    const float* gw = &W[(size_t)(kt + bk0) * D_ + n0 + bcol];
#pragma unroll
    for (int j = 0; j < 8; ++j) rb[j] = gw[(size_t)j * D_];
  };
  auto writeLDS = [&]() {
    bf16x8 pb;
#pragma unroll
    for (int j = 0; j < 8; ++j) pb[j] = (short)f2bf(rb[j]);
    *(bf16x8*)&Als[arow * 40 + akq] = pa;
    *(bf16x8*)&Bls[bcol * 40 + bk0] = pb;
  };
  auto compute = [&]() {
    bf16x8 a0 = *(const bf16x8*)&Als[(wr * 32 + lrow) * 40 + lk];
    bf16x8 a1 = *(const bf16x8*)&Als[(wr * 32 + 16 + lrow) * 40 + lk];
    bf16x8 b0 = *(const bf16x8*)&Bls[(wc * 32 + lrow) * 40 + lk];
    bf16x8 b1 = *(const bf16x8*)&Bls[(wc * 32 + 16 + lrow) * 40 + lk];
    acc[0][0] = __builtin_amdgcn_mfma_f32_16x16x32_bf16(a0, b0, acc[0][0], 0, 0, 0);
    acc[0][1] = __builtin_amdgcn_mfma_f32_16x16x32_bf16(a0, b1, acc[0][1], 0, 0, 0);
    acc[1][0] = __builtin_amdgcn_mfma_f32_16x16x32_bf16(a1, b0, acc[1][0], 0, 0, 0);
    acc[1][1] = __builtin_amdgcn_mfma_f32_16x16x32_bf16(a1, b1, acc[1][1], 0, 0, 0);
  };

  loadAB(0);
  writeLDS();
  for (int kt = 32; kt < D_; kt += 32) {
    loadAB(kt);
    __syncthreads();
    compute();
    __syncthreads();
    writeLDS();
  }
  __syncthreads();
  compute();

#pragma unroll
  for (int j = 0; j < 2; ++j) {
    const int col = n0 + wc * 32 + j * 16 + lrow;
    const float bv4 = bias[col];
#pragma unroll
    for (int i = 0; i < 2; ++i) {
#pragma unroll
      for (int r = 0; r < 4; ++r) {
        const int row = m0 + wr * 32 + i * 16 + (lane >> 4) * 4 + r;
        out[(size_t)row * D_ + col] = acc[i][j][r] + bv4;
      }
    }
  }
}

// ---------------------------------------------------------------------------
extern "C" void kernel_launch(void* const* d_in, const int* in_sizes, int n_in,
                              void* d_out, int out_size, void* d_ws, size_t ws_size,
                              hipStream_t stream) {
  (void)in_sizes; (void)n_in; (void)out_size; (void)ws_size;
  const float* queries = (const float*)d_in[0];
  const float* keys    = (const float*)d_in[1];
  const float* values  = (const float*)d_in[2];
  const float* Wq = (const float*)d_in[3];
  const float* bq = (const float*)d_in[4];
  const float* Wk = (const float*)d_in[5];
  const float* bk = (const float*)d_in[6];
  const float* Wv = (const float*)d_in[7];
  const float* bv = (const float*)d_in[8];
  const float* Wo = (const float*)d_in[9];
  const float* bo = (const float*)d_in[10];

  float* ws = (float*)d_ws;
  const size_t seg = (size_t)BH_ * L_ * DH_;  // 1,048,576 floats
  float* Qb  = ws;
  float* Kb  = Qb + seg;
  float* Vb  = Kb + seg;
  float* KVb = Vb + seg;                        // [BH, NC, DH, DH] raw chunk sums
  float* p   = KVb + (size_t)BH_ * NC_ * DH_ * DH_;
  float* qscale = p; p += BH_ * L_;
  float* salloc = p; p += BH_ * L_;
  float* comp   = p; p += BH_ * L_;
  float* si_a   = p; p += BH_ * L_;
  float* so_a   = p; p += BH_ * L_;
  float* e_a    = p; p += BH_ * L_;
  float* sumQ   = p; p += BH_ * NC_ * DH_;
  float* sumK   = p; p += BH_ * NC_ * DH_;
  float* sumQSI = p; p += BH_ * NC_ * DH_;
  float* sumKSO = p; p += BH_ * NC_ * DH_;
  float* sumE   = p; p += BH_ * NC_;
  unsigned short* Xb16 = (unsigned short*)p;    // [BL, D] bf16

  proj3_k<<<dim3(BL_ / 64, D_ / 64, 3), 256, 0, stream>>>(
      queries, keys, values, Wq, bq, Wk, bk, Wv, bv, Qb, Kb, Vb, sumQ, sumK);
  flow_phase1_k<<<BH_ * NC_, 256, 0, stream>>>(Qb, Kb, sumQ, sumK,
                                               qscale, si_a, so_a, sumQSI, sumKSO);
  flow_phase2_k<<<BH_ * NC_, 256, 0, stream>>>(Qb, Kb, sumQSI, sumKSO, si_a, so_a,
                                               salloc, e_a, sumE);
  flow_ckv_k<<<BH_ * NC_, 256, 0, stream>>>(Kb, Vb, e_a, sumE, comp, KVb);
  attn_k<<<BH_ * NC_, 256, 0, stream>>>(Qb, Kb, Vb, KVb, qscale, salloc, comp, Xb16);
  gemm_out_k<<<dim3(BL_ / 64, D_ / 64), 256, 0, stream>>>(Xb16, Wo, bo, (float*)d_out);
}

// Round 7
// 68.496 us; speedup vs baseline: 2.8601x; 1.8278x over previous
//
#include <hip/hip_runtime.h>
#include <math.h>

#define EPSF 1e-6f

constexpr int B_  = 2;
constexpr int L_  = 1024;
constexpr int D_  = 512;
constexpr int H_  = 8;
constexpr int DH_ = 64;
constexpr int BL_ = B_ * L_;   // 2048
constexpr int BH_ = B_ * H_;   // 16
constexpr int CT_ = 64;        // chunk length
constexpr int NC_ = L_ / CT_;  // 16 chunks

typedef __attribute__((ext_vector_type(8))) short bf16x8;
typedef __attribute__((ext_vector_type(4))) float f32x4;

__device__ __forceinline__ unsigned short f2bf(float f) {
  union { float f; unsigned int u; } v; v.f = f;
  const unsigned int u = v.u;
  return (unsigned short)((u + 0x7FFFu + ((u >> 16) & 1u)) >> 16);  // RNE
}

// Swizzled ushort index for a [64][64] bf16 LDS tile (128-B rows).
// XOR 16B-granule bits (col bits 3..5) with row bits 0..2 -> conflict-free
// b128 frag reads (cdna guide §6 G4).
__device__ __forceinline__ int sw(int row, int col) {
  return row * 64 + (col ^ ((row & 7) << 3));
}

// ---------------------------------------------------------------------------
// Fused projection GEMMs (z = 0:Q, 1:K, 2:V): out = sigmoid?(A @ W + b),
// permuted store to [B,H,L,Dh]; z<2 also writes per-(chunk,head) column sums.
// ---------------------------------------------------------------------------
__global__ __launch_bounds__(256) void proj3_k(const float* __restrict__ Qin,
                                               const float* __restrict__ Kin,
                                               const float* __restrict__ Vin,
                                               const float* __restrict__ Wq,
                                               const float* __restrict__ bq,
                                               const float* __restrict__ Wk,
                                               const float* __restrict__ bk,
                                               const float* __restrict__ Wv,
                                               const float* __restrict__ bv,
                                               float* __restrict__ Qb,
                                               float* __restrict__ Kb,
                                               float* __restrict__ Vb,
                                               float* __restrict__ sumQ,
                                               float* __restrict__ sumK) {
  const int z = blockIdx.z;
  const float* A    = (z == 0) ? Qin : (z == 1) ? Kin : Vin;
  const float* W    = (z == 0) ? Wq  : (z == 1) ? Wk  : Wv;
  const float* bias = (z == 0) ? bq  : (z == 1) ? bk  : bv;
  float* out        = (z == 0) ? Qb  : (z == 1) ? Kb  : Vb;
  float* csum       = (z == 0) ? sumQ : (z == 1) ? sumK : nullptr;
  const bool sig = (z < 2);

  __shared__ __align__(16) short Als[64 * 40];
  __shared__ __align__(16) short Bls[64 * 40];
  const int tid = threadIdx.x;
  const int m0 = blockIdx.x * 64, n0 = blockIdx.y * 64;
  const int arow = tid >> 2, akq = (tid & 3) << 3;
  const int bcol = tid & 63, bk0 = (tid >> 6) << 3;
  const int lane = tid & 63, wid = tid >> 6;
  const int wr = wid >> 1, wc = wid & 1;
  const int lrow = lane & 15, lk = (lane >> 4) << 3;

  f32x4 acc[2][2] = {{{0.f, 0.f, 0.f, 0.f}, {0.f, 0.f, 0.f, 0.f}},
                     {{0.f, 0.f, 0.f, 0.f}, {0.f, 0.f, 0.f, 0.f}}};
  float ra[8], rb[8];

  auto loadAB = [&](int kt) {
    const float4 f0 = *(const float4*)&A[(size_t)(m0 + arow) * D_ + kt + akq];
    const float4 f1 = *(const float4*)&A[(size_t)(m0 + arow) * D_ + kt + akq + 4];
    ra[0] = f0.x; ra[1] = f0.y; ra[2] = f0.z; ra[3] = f0.w;
    ra[4] = f1.x; ra[5] = f1.y; ra[6] = f1.z; ra[7] = f1.w;
    const float* gw = &W[(size_t)(kt + bk0) * D_ + n0 + bcol];
#pragma unroll
    for (int j = 0; j < 8; ++j) rb[j] = gw[(size_t)j * D_];
  };
  auto writeLDS = [&]() {
    bf16x8 pa, pb;
#pragma unroll
    for (int j = 0; j < 8; ++j) {
      pa[j] = (short)f2bf(ra[j]);
      pb[j] = (short)f2bf(rb[j]);
    }
    *(bf16x8*)&Als[arow * 40 + akq] = pa;
    *(bf16x8*)&Bls[bcol * 40 + bk0] = pb;
  };
  auto compute = [&]() {
    bf16x8 a0 = *(const bf16x8*)&Als[(wr * 32 + lrow) * 40 + lk];
    bf16x8 a1 = *(const bf16x8*)&Als[(wr * 32 + 16 + lrow) * 40 + lk];
    bf16x8 b0 = *(const bf16x8*)&Bls[(wc * 32 + lrow) * 40 + lk];
    bf16x8 b1 = *(const bf16x8*)&Bls[(wc * 32 + 16 + lrow) * 40 + lk];
    acc[0][0] = __builtin_amdgcn_mfma_f32_16x16x32_bf16(a0, b0, acc[0][0], 0, 0, 0);
    acc[0][1] = __builtin_amdgcn_mfma_f32_16x16x32_bf16(a0, b1, acc[0][1], 0, 0, 0);
    acc[1][0] = __builtin_amdgcn_mfma_f32_16x16x32_bf16(a1, b0, acc[1][0], 0, 0, 0);
    acc[1][1] = __builtin_amdgcn_mfma_f32_16x16x32_bf16(a1, b1, acc[1][1], 0, 0, 0);
  };

  loadAB(0);
  writeLDS();
  for (int kt = 32; kt < D_; kt += 32) {
    loadAB(kt);
    __syncthreads();
    compute();
    __syncthreads();
    writeLDS();
  }
  __syncthreads();
  compute();

  const int b = m0 >> 10, h = n0 >> 6;
  float psum[2] = {0.f, 0.f};
#pragma unroll
  for (int j = 0; j < 2; ++j) {
    const int col = n0 + wc * 32 + j * 16 + lrow;
    const float bv4 = bias[col];
    const int dh = col & 63;
#pragma unroll
    for (int i = 0; i < 2; ++i) {
#pragma unroll
      for (int r = 0; r < 4; ++r) {
        const int row = m0 + wr * 32 + i * 16 + (lane >> 4) * 4 + r;
        float x = acc[i][j][r] + bv4;
        if (sig) x = 1.0f / (1.0f + expf(-x));
        const int l = row & (L_ - 1);
        out[(((size_t)(b * H_ + h)) * L_ + l) * DH_ + dh] = x;
        psum[j] += x;
      }
    }
  }
  if (csum) {
    float* sumS = (float*)Als;
#pragma unroll
    for (int j = 0; j < 2; ++j) {
      psum[j] += __shfl_xor(psum[j], 16);
      psum[j] += __shfl_xor(psum[j], 32);
      if ((lane >> 4) == 0) sumS[wr * 64 + wc * 32 + j * 16 + lrow] = psum[j];
    }
    __syncthreads();
    if (tid < 64) {
      const int c = (m0 & (L_ - 1)) >> 6;
      const int bc = (b * H_ + h) * NC_ + c;
      csum[bc * DH_ + tid] = sumS[tid] + sumS[64 + tid];
    }
  }
}

// ---------------------------------------------------------------------------
// Flow phase 1: 256 thr, 4-wave d-split scans.
// ---------------------------------------------------------------------------
__global__ __launch_bounds__(256) void flow_phase1_k(const float* __restrict__ Qb,
                                                     const float* __restrict__ Kb,
                                                     const float* __restrict__ sumQ,
                                                     const float* __restrict__ sumK,
                                                     float* __restrict__ qscale,
                                                     float* __restrict__ si_a,
                                                     float* __restrict__ so_a,
                                                     float* __restrict__ sumQSI,
                                                     float* __restrict__ sumKSO) {
  const int bc = blockIdx.x, bh = bc >> 4, c = bc & (NC_ - 1);
  const int g = bc * CT_;
  const int tid = threadIdx.x, lane = tid & 63, w = tid >> 6;
  __shared__ float qS[64][65], kS[64][65];
  __shared__ float pqS[64], pkS[64];
  __shared__ float aS[4][64], bS[4][64];
  __shared__ float siS[64], soS[64];
  for (int i = tid; i < CT_ * DH_; i += 256) {
    const int row = i >> 6, d = i & 63;
    qS[row][d] = Qb[(size_t)g * DH_ + i];
    kS[row][d] = Kb[(size_t)g * DH_ + i];
  }
  if (tid < 64) {
    float pq = 0.f, pk = 0.f;
    for (int cc = 0; cc < c; ++cc) {
      pq += sumQ[(bh * NC_ + cc) * DH_ + tid];
      pk += sumK[(bh * NC_ + cc) * DH_ + tid];
    }
    pqS[tid] = pq; pkS[tid] = pk;
  }
  __syncthreads();
  float ap = 0.f, bp = 0.f;
  for (int dd = 0; dd < 16; ++dd) {
    const int d = w * 16 + dd;
    const float qv = qS[lane][d];
    const float kv = kS[lane][d];
    float ck = kv, cq = qv;
#pragma unroll
    for (int off = 1; off < 64; off <<= 1) {
      const float t1 = __shfl_up(ck, off);
      const float t2 = __shfl_up(cq, off);
      ck += (lane >= off) ? t1 : 0.f;
      cq += (lane >= off) ? t2 : 0.f;
    }
    ck += pkS[d];
    cq += pqS[d];
    ap += (qv + EPSF) * (ck + EPSF);
    bp += (kv + EPSF) * (cq + EPSF);
  }
  aS[w][lane] = ap; bS[w][lane] = bp;
  __syncthreads();
  const float normal = (float)(c * CT_ + lane + 1);
  if (w == 0) {
    const float a = aS[0][lane] + aS[1][lane] + aS[2][lane] + aS[3][lane];
    const float b = bS[0][lane] + bS[1][lane] + bS[2][lane] + bS[3][lane];
    const float si = normal / a, so = normal / b;
    qscale[g + lane] = 1.0f / a;
    si_a[g + lane] = si;
    so_a[g + lane] = so;
    siS[lane] = si; soS[lane] = so;
  }
  __syncthreads();
  float sq = 0.f, sk = 0.f;
#pragma unroll
  for (int li = 0; li < 16; ++li) {
    const int l = w * 16 + li;
    sq += qS[l][lane] * siS[l];
    sk += kS[l][lane] * soS[l];
  }
  aS[w][lane] = sq; bS[w][lane] = sk;
  __syncthreads();
  if (tid < 64) {
    sumQSI[bc * DH_ + tid] = aS[0][tid] + aS[1][tid] + aS[2][tid] + aS[3][tid];
    sumKSO[bc * DH_ + tid] = bS[0][tid] + bS[1][tid] + bS[2][tid] + bS[3][tid];
  }
}

// ---------------------------------------------------------------------------
// Flow phase 2: 256 thr, 4-wave d-split. Outputs salloc, e, chunk sumE.
// ---------------------------------------------------------------------------
__global__ __launch_bounds__(256) void flow_phase2_k(const float* __restrict__ Qb,
                                                     const float* __restrict__ Kb,
                                                     const float* __restrict__ sumQSI,
                                                     const float* __restrict__ sumKSO,
                                                     const float* __restrict__ si_a,
                                                     const float* __restrict__ so_a,
                                                     float* __restrict__ salloc,
                                                     float* __restrict__ e_a,
                                                     float* __restrict__ sumE) {
  const int bc = blockIdx.x, bh = bc >> 4, c = bc & (NC_ - 1);
  const int g = bc * CT_;
  const int tid = threadIdx.x, lane = tid & 63, w = tid >> 6;
  __shared__ float qS[64][65], kS[64][65];
  __shared__ float pqS[64], pkS[64];
  __shared__ float aS[4][64], bS[4][64];
  for (int i = tid; i < CT_ * DH_; i += 256) {
    const int row = i >> 6, d = i & 63;
    qS[row][d] = Qb[(size_t)g * DH_ + i];
    kS[row][d] = Kb[(size_t)g * DH_ + i];
  }
  if (tid < 64) {
    float pq = 0.f, pk = 0.f;
    for (int cc = 0; cc < c; ++cc) {
      pq += sumQSI[(bh * NC_ + cc) * DH_ + tid];
      pk += sumKSO[(bh * NC_ + cc) * DH_ + tid];
    }
    pqS[tid] = pq; pkS[tid] = pk;
  }
  __syncthreads();
  const float si = si_a[g + lane];
  const float so = so_a[g + lane];
  float c1p = 0.f, c2p = 0.f;
  for (int dd = 0; dd < 16; ++dd) {
    const int d = w * 16 + dd;
    const float qv = qS[lane][d];
    const float kv = kS[lane][d];
    float ckso = kv * so, cqsi = qv * si;
#pragma unroll
    for (int off = 1; off < 64; off <<= 1) {
      const float t1 = __shfl_up(ckso, off);
      const float t2 = __shfl_up(cqsi, off);
      ckso += (lane >= off) ? t1 : 0.f;
      cqsi += (lane >= off) ? t2 : 0.f;
    }
    ckso += pkS[d];
    cqsi += pqS[d];
    c1p += (qv + EPSF) * (ckso + EPSF);
    c2p += (kv + EPSF) * (cqsi + EPSF);
  }
  aS[w][lane] = c1p; bS[w][lane] = c2p;
  __syncthreads();
  if (w == 0) {
    const float c1 = aS[0][lane] + aS[1][lane] + aS[2][lane] + aS[3][lane];
    const float c2 = bS[0][lane] + bS[1][lane] + bS[2][lane] + bS[3][lane];
    const float normal = (float)(c * CT_ + lane + 1);
    const float cs_sink = c1 / normal;
    salloc[g + lane] = 1.0f / (1.0f + expf(-cs_sink));
    float cs_src = c2 / normal;
    cs_src = fminf(1.0f, fmaxf(-1.0f, cs_src));
    const float e = expf(cs_src);
    e_a[g + lane] = e;
    float tot = e;
#pragma unroll
    for (int off = 32; off; off >>= 1) tot += __shfl_xor(tot, off);
    if (lane == 0) sumE[bc] = tot;
  }
}

// ---------------------------------------------------------------------------
// Fused: source_competition (inline prefix of sumE) + chunk-local KV sums.
// ---------------------------------------------------------------------------
__global__ __launch_bounds__(256) void flow_ckv_k(const float* __restrict__ K,
                                                  const float* __restrict__ V,
                                                  const float* __restrict__ e_a,
                                                  const float* __restrict__ sumE,
                                                  float* __restrict__ comp,
                                                  float* __restrict__ KV) {
  const int bc = blockIdx.x, bh = bc >> 4, c = bc & (NC_ - 1);
  const int g = bc * CT_;
  const int tid = threadIdx.x;
  __shared__ float compS[CT_];
  __shared__ float kb[CT_][DH_];
  __shared__ float vb[CT_][DH_];
  if (tid < 64) {
    const int lane = tid;
    const float e = e_a[g + lane];
    float se = (lane < c) ? sumE[bh * NC_ + lane] : 0.f;
#pragma unroll
    for (int off = 32; off; off >>= 1) se += __shfl_xor(se, off);
    float s = e;
#pragma unroll
    for (int off = 1; off < 64; off <<= 1) {
      const float t = __shfl_up(s, off);
      s += (lane >= off) ? t : 0.f;
    }
    const float cf = e / (se + s) * (float)(c * CT_ + lane + 1);
    compS[lane] = cf;
    comp[g + lane] = cf;
  }
  __syncthreads();
  const float* k = K + (size_t)g * DH_;
  const float* v = V + (size_t)g * DH_;
  for (int i = tid; i < CT_ * DH_; i += 256) {
    const int l = i >> 6;
    kb[l][i & 63] = k[i];
    vb[l][i & 63] = v[i] * compS[l];
  }
  __syncthreads();
  const int m = tid & 63, dg = tid >> 6;
  float acc[16] = {};
  for (int l = 0; l < CT_; ++l) {
    const float vm = vb[l][m];
#pragma unroll
    for (int i = 0; i < 16; ++i) acc[i] += kb[l][dg * 16 + i] * vm;
  }
  float* out = KV + ((size_t)bc * DH_ + dg * 16) * DH_ + m;
#pragma unroll
  for (int i = 0; i < 16; ++i) out[i * DH_] = acc[i];
}

// ---------------------------------------------------------------------------
// Distributed exclusive prefix over chunks of KV, in place.
// 1 element/thread, unrolled over NC -> pipelined loads. grid BH*NC x 256.
// ---------------------------------------------------------------------------
__global__ __launch_bounds__(256) void kv_prefix_k(float* __restrict__ KV) {
  const int idx = blockIdx.x * 256 + threadIdx.x;  // 0..65535
  const int bh = idx >> 12, p = idx & 4095;
  const size_t base = (size_t)bh * NC_ * DH_ * DH_ + p;
  float run = 0.f;
#pragma unroll
  for (int c = 0; c < NC_; ++c) {
    const float t = KV[base + (size_t)c * DH_ * DH_];
    KV[base + (size_t)c * DH_ * DH_] = run;
    run += t;
  }
}

// ---------------------------------------------------------------------------
// MFMA attention. Block = one (bh, chunk), 256 thr = 4 waves; wave w owns
// output rows [16w, 16w+16). All operands staged bf16 in swizzled [64][64]
// LDS tiles. X = (qp @ KVp + tril(qp k^T) @ v') * salloc, bf16 out.
// ---------------------------------------------------------------------------
__global__ __launch_bounds__(256) void attn_k(const float* __restrict__ Q,
                                              const float* __restrict__ K,
                                              const float* __restrict__ V,
                                              const float* __restrict__ KVp,
                                              const float* __restrict__ qscale,
                                              const float* __restrict__ salloc,
                                              const float* __restrict__ comp,
                                              unsigned short* __restrict__ X) {
  const int bc = blockIdx.x;
  const int bh = bc >> 4, c = bc & (NC_ - 1);
  const int bb = bh >> 3, hh = bh & (H_ - 1);
  const int g = bc * CT_;
  __shared__ __align__(16) unsigned short qp16[64 * 64];  // [l][d]
  __shared__ __align__(16) unsigned short k16[64 * 64];   // [j][d]
  __shared__ __align__(16) unsigned short vT16[64 * 64];  // [m][j] = v'[j][m]
  __shared__ __align__(16) unsigned short kvT16[64 * 64]; // [m][d] = KVp[d][m]
  __shared__ __align__(16) unsigned short S16[64 * 64];   // [l][j] masked scores
  const int tid = threadIdx.x;
  // staging: global coalesced reads; vT/kvT transposed into LDS
  for (int i = tid; i < 64 * 64; i += 256) {
    const int r = i >> 6, d = i & 63;  // r = row in source, d = col in source
    qp16[sw(r, d)] = f2bf(Q[(size_t)g * DH_ + i] * qscale[g + r]);
    k16[sw(r, d)] = f2bf(K[(size_t)g * DH_ + i]);
    vT16[sw(d, r)] = f2bf(V[(size_t)g * DH_ + i] * comp[g + r]);
    kvT16[sw(d, r)] = f2bf(KVp[(size_t)bc * DH_ * DH_ + i]);
  }
  __syncthreads();

  const int lane = tid & 63, w = tid >> 6;
  const int fr = lane & 15, fk = (lane >> 4) << 3;  // frag row/col, k-offset
  const int arow = w * 16 + fr;
  f32x4 accX[4] = {{0.f, 0.f, 0.f, 0.f}, {0.f, 0.f, 0.f, 0.f},
                   {0.f, 0.f, 0.f, 0.f}, {0.f, 0.f, 0.f, 0.f}};
  f32x4 accS[4] = {{0.f, 0.f, 0.f, 0.f}, {0.f, 0.f, 0.f, 0.f},
                   {0.f, 0.f, 0.f, 0.f}, {0.f, 0.f, 0.f, 0.f}};

  const bf16x8 aq0 = *(const bf16x8*)&qp16[sw(arow, fk)];
  const bf16x8 aq1 = *(const bf16x8*)&qp16[sw(arow, fk + 32)];
#pragma unroll
  for (int cb = 0; cb < 4; ++cb) {
    const int bcol = cb * 16 + fr;
    const bf16x8 bv0 = *(const bf16x8*)&kvT16[sw(bcol, fk)];
    const bf16x8 bv1 = *(const bf16x8*)&kvT16[sw(bcol, fk + 32)];
    accX[cb] = __builtin_amdgcn_mfma_f32_16x16x32_bf16(aq0, bv0, accX[cb], 0, 0, 0);
    accX[cb] = __builtin_amdgcn_mfma_f32_16x16x32_bf16(aq1, bv1, accX[cb], 0, 0, 0);
    const bf16x8 bk0 = *(const bf16x8*)&k16[sw(bcol, fk)];
    const bf16x8 bk1 = *(const bf16x8*)&k16[sw(bcol, fk + 32)];
    accS[cb] = __builtin_amdgcn_mfma_f32_16x16x32_bf16(aq0, bk0, accS[cb], 0, 0, 0);
    accS[cb] = __builtin_amdgcn_mfma_f32_16x16x32_bf16(aq1, bk1, accS[cb], 0, 0, 0);
  }
  // mask (tril incl. diag) + bf16 writeback of S. C layout: row=(lane>>4)*4+r.
#pragma unroll
  for (int cb = 0; cb < 4; ++cb) {
#pragma unroll
    for (int r = 0; r < 4; ++r) {
      const int l = w * 16 + (lane >> 4) * 4 + r;
      const int j = cb * 16 + fr;
      S16[sw(l, j)] = (j <= l) ? f2bf(accS[cb][r]) : (unsigned short)0;
    }
  }
  __syncthreads();
  // S @ v'
  const bf16x8 as0 = *(const bf16x8*)&S16[sw(arow, fk)];
  const bf16x8 as1 = *(const bf16x8*)&S16[sw(arow, fk + 32)];
#pragma unroll
  for (int cb = 0; cb < 4; ++cb) {
    const int bcol = cb * 16 + fr;
    const bf16x8 bv0 = *(const bf16x8*)&vT16[sw(bcol, fk)];
    const bf16x8 bv1 = *(const bf16x8*)&vT16[sw(bcol, fk + 32)];
    accX[cb] = __builtin_amdgcn_mfma_f32_16x16x32_bf16(as0, bv0, accX[cb], 0, 0, 0);
    accX[cb] = __builtin_amdgcn_mfma_f32_16x16x32_bf16(as1, bv1, accX[cb], 0, 0, 0);
  }
  // epilogue: * salloc, bf16 store to X [B, L, H*Dh]
#pragma unroll
  for (int r = 0; r < 4; ++r) {
    const int l = w * 16 + (lane >> 4) * 4 + r;
    const float sal = salloc[g + l];
    const size_t rowbase = ((size_t)(bb * L_ + c * CT_ + l)) * D_ + hh * DH_;
#pragma unroll
    for (int cb = 0; cb < 4; ++cb) {
      const int m = cb * 16 + fr;
      X[rowbase + m] = f2bf(accX[cb][r] * sal);
    }
  }
}

// ---------------------------------------------------------------------------
// Output GEMM: d_out = X(bf16) @ Wo + bo.
// ---------------------------------------------------------------------------
__global__ __launch_bounds__(256) void gemm_out_k(const unsigned short* __restrict__ A,
                                                  const float* __restrict__ W,
                                                  const float* __restrict__ bias,
                                                  float* __restrict__ out) {
  __shared__ __align__(16) short Als[64 * 40];
  __shared__ __align__(16) short Bls[64 * 40];
  const int tid = threadIdx.x;
  const int m0 = blockIdx.x * 64, n0 = blockIdx.y * 64;
  const int arow = tid >> 2, akq = (tid & 3) << 3;
  const int bcol = tid & 63, bk0 = (tid >> 6) << 3;
  const int lane = tid & 63, wid = tid >> 6;
  const int wr = wid >> 1, wc = wid & 1;
  const int lrow = lane & 15, lk = (lane >> 4) << 3;

  f32x4 acc[2][2] = {{{0.f, 0.f, 0.f, 0.f}, {0.f, 0.f, 0.f, 0.f}},
                     {{0.f, 0.f, 0.f, 0.f}, {0.f, 0.f, 0.f, 0.f}}};
  bf16x8 pa;
  float rb[8];
  auto loadAB = [&](int kt) {
    pa = *(const bf16x8*)&A[(size_t)(m0 + arow) * D_ + kt + akq];
    const float* gw = &W[(size_t)(kt + bk0) * D_ + n0 + bcol];
#pragma unroll
    for (int j = 0; j < 8; ++j) rb[j] = gw[(size_t)j * D_];
  };
  auto writeLDS = [&]() {
    bf16x8 pb;
#pragma unroll
    for (int j = 0; j < 8; ++j) pb[j] = (short)f2bf(rb[j]);
    *(bf16x8*)&Als[arow * 40 + akq] = pa;
    *(bf16x8*)&Bls[bcol * 40 + bk0] = pb;
  };
  auto compute = [&]() {
    bf16x8 a0 = *(const bf16x8*)&Als[(wr * 32 + lrow) * 40 + lk];
    bf16x8 a1 = *(const bf16x8*)&Als[(wr * 32 + 16 + lrow) * 40 + lk];
    bf16x8 b0 = *(const bf16x8*)&Bls[(wc * 32 + lrow) * 40 + lk];
    bf16x8 b1 = *(const bf16x8*)&Bls[(wc * 32 + 16 + lrow) * 40 + lk];
    acc[0][0] = __builtin_amdgcn_mfma_f32_16x16x32_bf16(a0, b0, acc[0][0], 0, 0, 0);
    acc[0][1] = __builtin_amdgcn_mfma_f32_16x16x32_bf16(a0, b1, acc[0][1], 0, 0, 0);
    acc[1][0] = __builtin_amdgcn_mfma_f32_16x16x32_bf16(a1, b0, acc[1][0], 0, 0, 0);
    acc[1][1] = __builtin_amdgcn_mfma_f32_16x16x32_bf16(a1, b1, acc[1][1], 0, 0, 0);
  };

  loadAB(0);
  writeLDS();
  for (int kt = 32; kt < D_; kt += 32) {
    loadAB(kt);
    __syncthreads();
    compute();
    __syncthreads();
    writeLDS();
  }
  __syncthreads();
  compute();

#pragma unroll
  for (int j = 0; j < 2; ++j) {
    const int col = n0 + wc * 32 + j * 16 + lrow;
    const float bv4 = bias[col];
#pragma unroll
    for (int i = 0; i < 2; ++i) {
#pragma unroll
      for (int r = 0; r < 4; ++r) {
        const int row = m0 + wr * 32 + i * 16 + (lane >> 4) * 4 + r;
        out[(size_t)row * D_ + col] = acc[i][j][r] + bv4;
      }
    }
  }
}

// ---------------------------------------------------------------------------
extern "C" void kernel_launch(void* const* d_in, const int* in_sizes, int n_in,
                              void* d_out, int out_size, void* d_ws, size_t ws_size,
                              hipStream_t stream) {
  (void)in_sizes; (void)n_in; (void)out_size; (void)ws_size;
  const float* queries = (const float*)d_in[0];
  const float* keys    = (const float*)d_in[1];
  const float* values  = (const float*)d_in[2];
  const float* Wq = (const float*)d_in[3];
  const float* bq = (const float*)d_in[4];
  const float* Wk = (const float*)d_in[5];
  const float* bk = (const float*)d_in[6];
  const float* Wv = (const float*)d_in[7];
  const float* bv = (const float*)d_in[8];
  const float* Wo = (const float*)d_in[9];
  const float* bo = (const float*)d_in[10];

  float* ws = (float*)d_ws;
  const size_t seg = (size_t)BH_ * L_ * DH_;  // 1,048,576 floats
  float* Qb  = ws;
  float* Kb  = Qb + seg;
  float* Vb  = Kb + seg;
  float* KVb = Vb + seg;                        // [BH, NC, DH, DH]
  float* p   = KVb + (size_t)BH_ * NC_ * DH_ * DH_;
  float* qscale = p; p += BH_ * L_;
  float* salloc = p; p += BH_ * L_;
  float* comp   = p; p += BH_ * L_;
  float* si_a   = p; p += BH_ * L_;
  float* so_a   = p; p += BH_ * L_;
  float* e_a    = p; p += BH_ * L_;
  float* sumQ   = p; p += BH_ * NC_ * DH_;
  float* sumK   = p; p += BH_ * NC_ * DH_;
  float* sumQSI = p; p += BH_ * NC_ * DH_;
  float* sumKSO = p; p += BH_ * NC_ * DH_;
  float* sumE   = p; p += BH_ * NC_;
  unsigned short* Xb16 = (unsigned short*)p;    // [BL, D] bf16

  proj3_k<<<dim3(BL_ / 64, D_ / 64, 3), 256, 0, stream>>>(
      queries, keys, values, Wq, bq, Wk, bk, Wv, bv, Qb, Kb, Vb, sumQ, sumK);
  flow_phase1_k<<<BH_ * NC_, 256, 0, stream>>>(Qb, Kb, sumQ, sumK,
                                               qscale, si_a, so_a, sumQSI, sumKSO);
  flow_phase2_k<<<BH_ * NC_, 256, 0, stream>>>(Qb, Kb, sumQSI, sumKSO, si_a, so_a,
                                               salloc, e_a, sumE);
  flow_ckv_k<<<BH_ * NC_, 256, 0, stream>>>(Kb, Vb, e_a, sumE, comp, KVb);
  kv_prefix_k<<<BH_ * NC_, 256, 0, stream>>>(KVb);
  attn_k<<<BH_ * NC_, 256, 0, stream>>>(Qb, Kb, Vb, KVb, qscale, salloc, comp, Xb16);
  gemm_out_k<<<dim3(BL_ / 64, D_ / 64), 256, 0, stream>>>(Xb16, Wo, bo, (float*)d_out);
}